// Round 1
// baseline (468.008 us; speedup 1.0000x reference)
//
#include <hip/hip_runtime.h>
#include <hip/hip_bf16.h>

#define B_ 4
#define N_ 4096
#define C_ 64
#define R_ 16
#define EPS_ 1e-12f

typedef __attribute__((ext_vector_type(8))) short bf16x8;
typedef __attribute__((ext_vector_type(4))) float f32x4;

static __device__ __forceinline__ unsigned short f2bf(float f) {
    unsigned int u = __float_as_uint(f);
    unsigned int r = (u + 0x7fffu + ((u >> 16) & 1u)) >> 16;
    return (unsigned short)r;
}
static __device__ __forceinline__ float bf2f(unsigned short us) {
    return __uint_as_float(((unsigned int)us) << 16);
}

// Pass 1: for tile pair (ti<=tj), compute K0 = 0.5*(W+W^T)*sigmoid(U U^T) once,
// write both orientations (bf16), accumulate row sums into deg (fp32 atomics).
__global__ __launch_bounds__(256) void k_pass1(
    const float* __restrict__ W, const float* __restrict__ U,
    unsigned short* __restrict__ K0, float* __restrict__ deg)
{
    const int tj = blockIdx.x, ti = blockIdx.y;
    if (ti > tj) return;
    const int I = ti * 64, J = tj * 64;
    const bool diag = (ti == tj);
    const int t = threadIdx.x;
    const int ii = t >> 2, g = t & 3, jjg = g * 16;

    __shared__ float UJ[64][17];
    __shared__ float Wc[64][65];
    __shared__ __align__(16) unsigned short K0s[64][72]; // 144B rows, 16B aligned
    __shared__ float rsum[64][4];
    __shared__ float csum[64][4];

    // stage U rows for J-block (coalesced float4)
    {
        const float4 v = *(const float4*)(U + (size_t)(J + (t >> 2)) * R_ + (t & 3) * 4);
        UJ[t >> 2][(t & 3) * 4 + 0] = v.x;
        UJ[t >> 2][(t & 3) * 4 + 1] = v.y;
        UJ[t >> 2][(t & 3) * 4 + 2] = v.z;
        UJ[t >> 2][(t & 3) * 4 + 3] = v.w;
    }
    // U row for this thread's I-row (4 lanes duplicate -> L1)
    float ui[16];
    {
        const float* up = U + (size_t)(I + ii) * R_;
        #pragma unroll
        for (int h = 0; h < 4; h++) {
            float4 v = *(const float4*)(up + 4 * h);
            ui[4*h] = v.x; ui[4*h+1] = v.y; ui[4*h+2] = v.z; ui[4*h+3] = v.w;
        }
    }
    __syncthreads();

    // A tile values for this thread's 16 elements (batch-independent)
    float a[16];
    #pragma unroll
    for (int q = 0; q < 16; q++) {
        float s = 0.f;
        #pragma unroll
        for (int k = 0; k < 16; k++) s += ui[k] * UJ[jjg + q][k];
        a[q] = 1.0f / (1.0f + __expf(-s));
    }

    for (int b = 0; b < B_; b++) {
        // stage W[b, J-rows, I-cols] (coalesced) for transpose access
        #pragma unroll
        for (int k = 0; k < 4; k++) {
            int idx = t + 256 * k;
            int row = idx >> 4, c4 = idx & 15;
            const float4 v = *(const float4*)(W + ((size_t)(b * N_ + J + row)) * N_ + I + c4 * 4);
            Wc[row][c4*4+0] = v.x; Wc[row][c4*4+1] = v.y;
            Wc[row][c4*4+2] = v.z; Wc[row][c4*4+3] = v.w;
        }
        // W[b, I+ii, J+jjg .. +15] direct to registers (coalesced float4)
        float wr[16];
        {
            const float* wp = W + ((size_t)(b * N_ + I + ii)) * N_ + J + jjg;
            #pragma unroll
            for (int h = 0; h < 4; h++) {
                float4 v = *(const float4*)(wp + 4 * h);
                wr[4*h] = v.x; wr[4*h+1] = v.y; wr[4*h+2] = v.z; wr[4*h+3] = v.w;
            }
        }
        __syncthreads(); // Wc ready

        float sumI = 0.f;
        unsigned int pk[8];
        #pragma unroll
        for (int q = 0; q < 16; q++) {
            float k0 = 0.5f * (wr[q] + Wc[jjg + q][ii]) * a[q];
            sumI += k0;
            unsigned short us = f2bf(k0);
            if (q & 1) pk[q >> 1] |= ((unsigned int)us) << 16;
            else       pk[q >> 1] = us;
        }
        // LDS copy (for transpose phase) + direct global write, both vectorized
        *(int4*)(&K0s[ii][jjg])     = make_int4(pk[0], pk[1], pk[2], pk[3]);
        *(int4*)(&K0s[ii][jjg + 8]) = make_int4(pk[4], pk[5], pk[6], pk[7]);
        {
            unsigned short* dst = K0 + ((size_t)(b * N_ + I + ii)) * N_ + J + jjg;
            *(int4*)(dst)     = make_int4(pk[0], pk[1], pk[2], pk[3]);
            *(int4*)(dst + 8) = make_int4(pk[4], pk[5], pk[6], pk[7]);
        }
        rsum[ii][g] = sumI;
        __syncthreads(); // K0s + rsum ready

        if (t < 64) {
            float s = rsum[t][0] + rsum[t][1] + rsum[t][2] + rsum[t][3];
            atomicAdd(deg + b * N_ + I + t, s);
        }
        if (!diag) {
            const int jj = t >> 2, iig = (t & 3) * 16;
            float cs = 0.f;
            unsigned int pko[8];
            #pragma unroll
            for (int q = 0; q < 16; q++) {
                unsigned short us = K0s[iig + q][jj];
                cs += bf2f(us);
                if (q & 1) pko[q >> 1] |= ((unsigned int)us) << 16;
                else       pko[q >> 1] = us;
            }
            unsigned short* dst = K0 + ((size_t)(b * N_ + J + jj)) * N_ + I + iig;
            *(int4*)(dst)     = make_int4(pko[0], pko[1], pko[2], pko[3]);
            *(int4*)(dst + 8) = make_int4(pko[4], pko[5], pko[6], pko[7]);
            csum[jj][t & 3] = cs;
        }
        __syncthreads(); // csum ready; all K0s/Wc reads done

        if (!diag && t < 64) {
            float s = csum[t][0] + csum[t][1] + csum[t][2] + csum[t][3];
            atomicAdd(deg + b * N_ + J + t, s);
        }
    }
}

// xdT[b, c, j] = bf16( x[b, j, c] * rsqrt(max(deg[b,j],EPS)) )  (64x64 LDS transpose)
__global__ __launch_bounds__(256) void k_xdT(
    const float* __restrict__ x, const float* __restrict__ deg,
    unsigned short* __restrict__ xdT)
{
    const int jt = blockIdx.x, b = blockIdx.y;
    const int J = jt * 64, t = threadIdx.x;
    __shared__ float xt[64][68];
    #pragma unroll
    for (int k = 0; k < 4; k++) {
        int idx = t + 256 * k;
        int row = idx >> 4, f4 = idx & 15;
        float d = rsqrtf(fmaxf(deg[b * N_ + J + row], EPS_));
        float4 v = *(const float4*)(x + ((size_t)(b * N_ + J + row)) * C_ + f4 * 4);
        xt[row][f4*4+0] = v.x * d; xt[row][f4*4+1] = v.y * d;
        xt[row][f4*4+2] = v.z * d; xt[row][f4*4+3] = v.w * d;
    }
    __syncthreads();
    const int c = t >> 2, jg = (t & 3) * 16;
    unsigned int pk[8];
    #pragma unroll
    for (int q = 0; q < 16; q++) {
        unsigned short us = f2bf(xt[jg + q][c]);
        if (q & 1) pk[q >> 1] |= ((unsigned int)us) << 16;
        else       pk[q >> 1] = us;
    }
    unsigned short* dst = xdT + ((size_t)(b * C_ + c)) * N_ + J + jg;
    *(int4*)(dst)     = make_int4(pk[0], pk[1], pk[2], pk[3]);
    *(int4*)(dst + 8) = make_int4(pk[4], pk[5], pk[6], pk[7]);
}

// Pass 2: out[b, I..I+31, :] = (wsc * d_i) * K0[b] @ xd[b]   via bf16 MFMA 16x16x32
__global__ __launch_bounds__(256) void k_gemm(
    const unsigned short* __restrict__ K0, const unsigned short* __restrict__ xdT,
    const float* __restrict__ deg, const float* __restrict__ wsc_p,
    float* __restrict__ out)
{
    const int rb = blockIdx.x, b = blockIdx.y;
    const int I = rb * 32;
    const int t = threadIdx.x, l = t & 63, w = t >> 6;
    __shared__ __align__(16) unsigned short As[32 * 64];
    __shared__ __align__(16) unsigned short Bs[64 * 64];
    f32x4 acc0 = {0.f, 0.f, 0.f, 0.f}, acc1 = {0.f, 0.f, 0.f, 0.f};

    const int ak = (t & 7) * 8;
    const size_t abase  = ((size_t)(b * N_ + I + (t >> 3))) * N_ + ak;
    const size_t bbase0 = ((size_t)(b * C_ + (t >> 3))) * N_ + ak;
    const size_t bbase1 = ((size_t)(b * C_ + 32 + (t >> 3))) * N_ + ak;
    const int rw = (w & 1) * 16, cw = (w >> 1) * 32;
    const int fr = l & 15, fq = l >> 4;

    int4 va  = *(const int4*)(K0  + abase);
    int4 vb0 = *(const int4*)(xdT + bbase0);
    int4 vb1 = *(const int4*)(xdT + bbase1);

    for (int kt = 0; kt < 64; kt++) {
        __syncthreads();
        ((int4*)As)[t]       = va;
        ((int4*)Bs)[t]       = vb0;
        ((int4*)Bs)[256 + t] = vb1;
        __syncthreads();
        if (kt < 63) { // prefetch next tile (overlaps with MFMA below)
            const int kb = (kt + 1) * 64;
            va  = *(const int4*)(K0  + abase + kb);
            vb0 = *(const int4*)(xdT + bbase0 + kb);
            vb1 = *(const int4*)(xdT + bbase1 + kb);
        }
        #pragma unroll
        for (int kk = 0; kk < 2; kk++) {
            bf16x8 af  = *(const bf16x8*)(As + (rw + fr) * 64 + kk * 32 + fq * 8);
            bf16x8 bf0 = *(const bf16x8*)(Bs + (cw + fr) * 64 + kk * 32 + fq * 8);
            bf16x8 bf1 = *(const bf16x8*)(Bs + (cw + 16 + fr) * 64 + kk * 32 + fq * 8);
            acc0 = __builtin_amdgcn_mfma_f32_16x16x32_bf16(af, bf0, acc0, 0, 0, 0);
            acc1 = __builtin_amdgcn_mfma_f32_16x16x32_bf16(af, bf1, acc1, 0, 0, 0);
        }
    }

    const float wsc = wsc_p[0];
    #pragma unroll
    for (int r = 0; r < 4; r++) {
        int row = I + rw + fq * 4 + r;
        float sc = wsc * rsqrtf(fmaxf(deg[b * N_ + row], EPS_));
        out[((size_t)(b * N_ + row)) * C_ + cw + fr]      = sc * acc0[r];
        out[((size_t)(b * N_ + row)) * C_ + cw + 16 + fr] = sc * acc1[r];
    }
}

extern "C" void kernel_launch(void* const* d_in, const int* in_sizes, int n_in,
                              void* d_out, int out_size, void* d_ws, size_t ws_size,
                              hipStream_t stream)
{
    const float* x   = (const float*)d_in[0];
    const float* W   = (const float*)d_in[1];
    const float* U   = (const float*)d_in[2];
    const float* wsc = (const float*)d_in[3];
    float* out = (float*)d_out;

    // workspace layout: K0 (bf16, 128 MiB) | deg (fp32, 64 KiB) | xdT (bf16, 2 MiB)
    unsigned short* K0  = (unsigned short*)d_ws;
    float*          deg = (float*)((char*)d_ws + (size_t)B_ * N_ * N_ * 2);
    unsigned short* xdT = (unsigned short*)((char*)deg + (size_t)B_ * N_ * 4);

    hipMemsetAsync(deg, 0, (size_t)B_ * N_ * sizeof(float), stream);
    hipLaunchKernelGGL(k_pass1, dim3(64, 64), dim3(256), 0, stream, W, U, K0, deg);
    hipLaunchKernelGGL(k_xdT,  dim3(64, 4),  dim3(256), 0, stream, x, deg, xdT);
    hipLaunchKernelGGL(k_gemm, dim3(128, 4), dim3(256), 0, stream, K0, xdT, deg, wsc, out);
}